// Round 1
// baseline (110.000 us; speedup 1.0000x reference)
//
#include <hip/hip_runtime.h>

// Conv1d: out[b,c,i] = sum_{k=0}^{127} x[b,c,i+k] * w[k]
// B=32, C=512, L=4096, KL=128 -> rows=16384, Lo=3969.
//
// Strategy: bf16 MFMA band-matrix conv. One block per row.
//   D[m][n] = sum_k A[m][k] * Bband[k][n],  A[m][k] = x[i0+16m+k] (k=0..159),
//   Bband[k][n] = w[k-n] if 0<=k-n<128 else 0.
// 5x mfma_f32_16x16x32_bf16 per 16x16 output tile. Memory-bound (~528MB HBM).

#define NROWS 16384
#define LIN   4096
#define KLEN  128
#define LOUT  3969           // LIN - KLEN + 1
#define KTOT  160            // band K extent (covers k = n + d, n<16, d<128)
#define NSTEP 5              // KTOT / 32
#define XELEMS (LIN + KTOT)  // staged row + zero tail = 4256

typedef __attribute__((ext_vector_type(8))) short bf16x8;
typedef __attribute__((ext_vector_type(4))) float f32x4;

__device__ __forceinline__ unsigned short f2bf(float f) {
    // round-to-nearest-even fp32 -> bf16 (inputs are finite)
    unsigned int u = __float_as_uint(f);
    u += 0x7FFFu + ((u >> 16) & 1u);
    return (unsigned short)(u >> 16);
}

__global__ __launch_bounds__(256, 4)
void conv1d_mfma(const float* __restrict__ x, const float* __restrict__ w,
                 float* __restrict__ out) {
    __shared__ __align__(16) unsigned short xs[XELEMS];        // 8512 B
    __shared__ __align__(16) unsigned short ws[KLEN];          // 256 B
    __shared__ __align__(16) unsigned short bandT[16 * KTOT];  // 5120 B, bandT[n][k]

    const int t   = threadIdx.x;
    const int row = blockIdx.x;
    const float* xr = x + (size_t)row * LIN;

    // ---- stage x row fp32 -> bf16 into LDS (coalesced float4 loads) ----
    #pragma unroll
    for (int j = 0; j < 4; ++j) {
        const int e = 4 * (t + 256 * j);            // 0..4092 step 4
        const float4 v = *reinterpret_cast<const float4*>(xr + e);
        ushort4 p;
        p.x = f2bf(v.x); p.y = f2bf(v.y); p.z = f2bf(v.z); p.w = f2bf(v.w);
        *reinterpret_cast<ushort4*>(&xs[e]) = p;
    }
    // zero the 160-elem tail (band zeros multiply these; keep them finite 0)
    if (t < (XELEMS - LIN) / 4) {
        ushort4 z; z.x = 0; z.y = 0; z.z = 0; z.w = 0;
        *reinterpret_cast<ushort4*>(&xs[LIN + 4 * t]) = z;
    }
    if (t < KLEN) ws[t] = f2bf(w[t]);
    __syncthreads();

    // ---- build transposed band matrix: bandT[n][k] = w[k-n] or 0 ----
    #pragma unroll
    for (int s = 0; s < 10; ++s) {
        const int e = t + 256 * s;        // 0..2559 = 16 * 160
        const int n = e / KTOT;
        const int k = e - n * KTOT;
        const int d = k - n;
        bandT[e] = (unsigned(d) < (unsigned)KLEN) ? ws[d] : (unsigned short)0;
    }
    __syncthreads();

    const int lane = t & 63;
    const int g    = lane >> 4;   // 0..3
    const int nn   = lane & 15;   // 0..15
    const int wv   = t >> 6;      // wave id 0..3

    // B fragments (weight band), constant across all tiles of the row.
    // B[k_local][n]: lane holds k_local = 8*g + j (j=0..7), n = nn.
    bf16x8 bfrag[NSTEP];
    #pragma unroll
    for (int kb = 0; kb < NSTEP; ++kb)
        bfrag[kb] = *reinterpret_cast<const bf16x8*>(&bandT[nn * KTOT + kb * 32 + 8 * g]);

    float* outr = out + (size_t)row * LOUT;

    // ---- 16 tiles of 256 outputs; 4 waves x 4 iterations ----
    #pragma unroll
    for (int it = 0; it < 4; ++it) {
        const int i0 = 256 * (wv + 4 * it);
        // A[m][k_local]: lane holds m = nn, k_local = 8*g + j -> contiguous 16B
        const unsigned short* abase = &xs[i0 + 16 * nn + 8 * g];
        f32x4 acc = {0.f, 0.f, 0.f, 0.f};
        #pragma unroll
        for (int kb = 0; kb < NSTEP; ++kb) {
            const bf16x8 afrag = *reinterpret_cast<const bf16x8*>(abase + 32 * kb);
            acc = __builtin_amdgcn_mfma_f32_16x16x32_bf16(afrag, bfrag[kb], acc, 0, 0, 0);
        }
        // D: col n = lane&15, row m = 4*(lane>>4) + r  -> out[i0 + 16m + n]
        #pragma unroll
        for (int r = 0; r < 4; ++r) {
            const int oi = i0 + 64 * g + 16 * r + nn;
            if (oi < LOUT) outr[oi] = acc[r];
        }
    }
}

extern "C" void kernel_launch(void* const* d_in, const int* in_sizes, int n_in,
                              void* d_out, int out_size, void* d_ws, size_t ws_size,
                              hipStream_t stream) {
    const float* x = (const float*)d_in[0];
    const float* w = (const float*)d_in[1];
    float* o = (float*)d_out;
    hipLaunchKernelGGL(conv1d_mfma, dim3(NROWS), dim3(256), 0, stream, x, w, o);
}